// Round 17
// baseline (658.661 us; speedup 1.0000x reference)
//
#include <hip/hip_runtime.h>
#include <hip/hip_bf16.h>
#include <cstdint>

typedef __attribute__((ext_vector_type(8))) short bf16x8;
typedef __attribute__((ext_vector_type(4))) float f32x4;
typedef __attribute__((ext_vector_type(16))) float f32x16;

#define H_   16
#define HKV_ 2
#define DD   256
#define BB   2
#define SS   2048
#define EE   2048
#define MTOK (BB*SS)     // 4096
#define HD   (H_*DD)     // 4096

static __device__ __forceinline__ unsigned short f2bf(float f) {
  union { float f; unsigned u; } v; v.f = f;
  unsigned r = v.u + 0x7fffu + ((v.u >> 16) & 1u);
  return (unsigned short)(r >> 16);
}
static __device__ __forceinline__ float bf2f(unsigned short h) {
  union { unsigned u; float f; } v; v.u = ((unsigned)h) << 16;
  return v.f;
}

static __device__ __forceinline__ void gll16(const unsigned short* g, unsigned short* l) {
  __builtin_amdgcn_global_load_lds(
      (const __attribute__((address_space(1))) unsigned int*)g,
      (__attribute__((address_space(3))) unsigned int*)l, 16, 0, 0);
}

// ---------------- fp32 -> bf16 convert (vectorized) ----------------
__global__ __launch_bounds__(256) void ga_cvt(const float* __restrict__ in,
                                              unsigned short* __restrict__ out, int n) {
  int i = (blockIdx.x * 256 + threadIdx.x) * 4;
  if (i >= n) return;
  float4 v = *(const float4*)(in + i);
  ushort4 o;
  o.x = f2bf(v.x); o.y = f2bf(v.y); o.z = f2bf(v.z); o.w = f2bf(v.w);
  *(ushort4*)(out + i) = o;
}

// -------- transpose+convert: out[c][r] = bf16(in[r][c]), in is R x C --------
__global__ __launch_bounds__(256) void ga_transpose_wo(const float* __restrict__ in,
                                                       unsigned short* __restrict__ out,
                                                       int R, int C) {
  __shared__ float tile[64][65];
  int c0 = blockIdx.x * 64, r0 = blockIdx.y * 64;
  int tid = threadIdx.x;
#pragma unroll
  for (int it = 0; it < 16; ++it) {
    int idx = it * 256 + tid; int rr = idx >> 6, cc = idx & 63;
    tile[rr][cc] = in[(size_t)(r0 + rr) * C + c0 + cc];
  }
  __syncthreads();
#pragma unroll
  for (int it = 0; it < 16; ++it) {
    int idx = it * 256 + tid; int rr = idx >> 6, cc = idx & 63;
    out[(size_t)(c0 + rr) * R + r0 + cc] = f2bf(tile[cc][rr]);
  }
}

// -------- pack [Wq|Wk|Wv|Wg] transposed: out[n][k], n in [0,9216) --------
__global__ __launch_bounds__(256) void ga_pack_qkvg(const float* __restrict__ Wq,
                                                    const float* __restrict__ Wk,
                                                    const float* __restrict__ Wv,
                                                    const float* __restrict__ Wg,
                                                    unsigned short* __restrict__ out) {
  __shared__ float tile[64][65];
  int n0 = blockIdx.x * 64, k0 = blockIdx.y * 64;
  const float* src; int C, cbase;
  if (n0 < 4096)      { src = Wq; C = 4096; cbase = n0; }
  else if (n0 < 4608) { src = Wk; C = 512;  cbase = n0 - 4096; }
  else if (n0 < 5120) { src = Wv; C = 512;  cbase = n0 - 4608; }
  else                { src = Wg; C = 4096; cbase = n0 - 5120; }
  int tid = threadIdx.x;
#pragma unroll
  for (int it = 0; it < 16; ++it) {
    int idx = it * 256 + tid; int rr = idx >> 6, cc = idx & 63;
    tile[rr][cc] = src[(size_t)(k0 + rr) * C + cbase + cc];
  }
  __syncthreads();
#pragma unroll
  for (int it = 0; it < 16; ++it) {
    int idx = it * 256 + tid; int rr = idx >> 6, cc = idx & 63;
    out[(size_t)(n0 + rr) * EE + k0 + cc] = f2bf(tile[cc][rr]);
  }
}

// ---- 128x128 GEMM loop (GEMM2), triple-buffered depth-2, counted vmcnt ----
// Verified R16 machinery: chunk-XOR swizzle row bits 2-3, both sides.
template<int KDIM>
static __device__ __forceinline__ void gemm_loop(const unsigned short* __restrict__ A,
                                                 const unsigned short* __restrict__ Bt,
                                                 unsigned short* As, unsigned short* Bs,
                                                 int m0, int n0, f32x4 acc[4][4]) {
  int tid = threadIdx.x, lane = tid & 63, wid = tid >> 6;
  int wr = wid >> 1, wc = wid & 1;
  int li = lane & 15, lg = lane >> 4;
  int xsw = (li >> 2) & 3;                  // lane-constant read-side XOR
  int rowA[2], cb8[2], ldso[2];
#pragma unroll
  for (int r2 = 0; r2 < 2; ++r2) {
    int c = r2 * 256 + wid * 64 + lane;
    rowA[r2] = c >> 2;
    cb8[r2] = (((c & 3) ^ ((c >> 4) & 3)) * 8);
    ldso[r2] = (r2 * 256 + wid * 64) * 8;   // wave-uniform LDS base (elems)
  }
#pragma unroll
  for (int p = 0; p < 2; ++p) {
#pragma unroll
    for (int r2 = 0; r2 < 2; ++r2) {
      gll16(A  + (size_t)(m0 + rowA[r2]) * KDIM + p * 32 + cb8[r2], As + p * 4096 + ldso[r2]);
      gll16(Bt + (size_t)(n0 + rowA[r2]) * KDIM + p * 32 + cb8[r2], Bs + p * 4096 + ldso[r2]);
    }
  }
  asm volatile("s_waitcnt vmcnt(4)" ::: "memory");   // batch 0 landed
  __builtin_amdgcn_s_barrier();

  const int NK = KDIM / 32;
  int cur = 0;
  for (int t = 0; t < NK; ++t) {
    unsigned short* Asc = As + cur * 4096;
    unsigned short* Bsc = Bs + cur * 4096;
    bool pre = (t + 2 < NK);
    if (pre) {
      int k0 = (t + 2) * 32;
      int wbuf = cur + 2; if (wbuf >= 3) wbuf -= 3;
      unsigned short* Asn = As + wbuf * 4096;
      unsigned short* Bsn = Bs + wbuf * 4096;
#pragma unroll
      for (int r2 = 0; r2 < 2; ++r2) {
        gll16(A  + (size_t)(m0 + rowA[r2]) * KDIM + k0 + cb8[r2], Asn + ldso[r2]);
        gll16(Bt + (size_t)(n0 + rowA[r2]) * KDIM + k0 + cb8[r2], Bsn + ldso[r2]);
      }
    }
    bf16x8 af[4], bfv[4];
#pragma unroll
    for (int mf = 0; mf < 4; ++mf)
      af[mf] = *(const bf16x8*)&Asc[(wr * 64 + mf * 16 + li) * 32 + ((lg ^ xsw) << 3)];
#pragma unroll
    for (int nf = 0; nf < 4; ++nf)
      bfv[nf] = *(const bf16x8*)&Bsc[(wc * 64 + nf * 16 + li) * 32 + ((lg ^ xsw) << 3)];
#pragma unroll
    for (int mf = 0; mf < 4; ++mf)
#pragma unroll
      for (int nf = 0; nf < 4; ++nf)
        acc[mf][nf] = __builtin_amdgcn_mfma_f32_16x16x32_bf16(af[mf], bfv[nf], acc[mf][nf], 0, 0, 0);
    if (pre) {
      asm volatile("s_waitcnt vmcnt(4)" ::: "memory");
    } else if (t + 1 < NK) {
      asm volatile("s_waitcnt vmcnt(0)" ::: "memory");
    }
    __builtin_amdgcn_sched_barrier(0);
    __builtin_amdgcn_s_barrier();
    ++cur; if (cur >= 3) cur -= 3;
  }
}

// ---- 256x128 GEMM loop (GEMM1): wave = 128x64 output, 2.67 MFMA/ds_read ----
// A tile 256x32 (4 chunks/thread), B tile 128x32 (2 chunks/thread); 6 loads/
// K-step -> counted vmcnt(6). Same swizzle/barrier discipline as gemm_loop.
template<int KDIM>
static __device__ __forceinline__ void gemm_loop_256(const unsigned short* __restrict__ A,
                                                     const unsigned short* __restrict__ Bt,
                                                     unsigned short* As, unsigned short* Bs,
                                                     int m0, int n0, f32x4 acc[8][4]) {
  int tid = threadIdx.x, lane = tid & 63, wid = tid >> 6;
  int wr = wid >> 1, wc = wid & 1;
  int li = lane & 15, lg = lane >> 4;
  int xsw = (li >> 2) & 3;
  int rowA[4], cbA[4], loA[4];
#pragma unroll
  for (int it = 0; it < 4; ++it) {
    int c = it * 256 + tid;
    rowA[it] = c >> 2;
    cbA[it] = (((c & 3) ^ ((c >> 4) & 3)) * 8);
    loA[it] = (it * 256 + wid * 64) * 8;
  }
  int rowB[2], cbB[2], loB[2];
#pragma unroll
  for (int it = 0; it < 2; ++it) {
    int c = it * 256 + tid;
    rowB[it] = c >> 2;
    cbB[it] = (((c & 3) ^ ((c >> 4) & 3)) * 8);
    loB[it] = (it * 256 + wid * 64) * 8;
  }
  // prologue: stage K-steps 0 and 1
#pragma unroll
  for (int p = 0; p < 2; ++p) {
#pragma unroll
    for (int it = 0; it < 4; ++it)
      gll16(A + (size_t)(m0 + rowA[it]) * KDIM + p * 32 + cbA[it], As + p * 8192 + loA[it]);
#pragma unroll
    for (int it = 0; it < 2; ++it)
      gll16(Bt + (size_t)(n0 + rowB[it]) * KDIM + p * 32 + cbB[it], Bs + p * 4096 + loB[it]);
  }
  asm volatile("s_waitcnt vmcnt(6)" ::: "memory");   // batch 0 landed
  __builtin_amdgcn_s_barrier();

  const int NK = KDIM / 32;
  int cur = 0;
  for (int t = 0; t < NK; ++t) {
    unsigned short* Asc = As + cur * 8192;
    unsigned short* Bsc = Bs + cur * 4096;
    bool pre = (t + 2 < NK);
    if (pre) {
      int k0 = (t + 2) * 32;
      int wbuf = cur + 2; if (wbuf >= 3) wbuf -= 3;
#pragma unroll
      for (int it = 0; it < 4; ++it)
        gll16(A + (size_t)(m0 + rowA[it]) * KDIM + k0 + cbA[it], As + wbuf * 8192 + loA[it]);
#pragma unroll
      for (int it = 0; it < 2; ++it)
        gll16(Bt + (size_t)(n0 + rowB[it]) * KDIM + k0 + cbB[it], Bs + wbuf * 4096 + loB[it]);
    }
    bf16x8 af[8], bfv[4];
#pragma unroll
    for (int mf = 0; mf < 8; ++mf)
      af[mf] = *(const bf16x8*)&Asc[(wr * 128 + mf * 16 + li) * 32 + ((lg ^ xsw) << 3)];
#pragma unroll
    for (int nf = 0; nf < 4; ++nf)
      bfv[nf] = *(const bf16x8*)&Bsc[(wc * 64 + nf * 16 + li) * 32 + ((lg ^ xsw) << 3)];
#pragma unroll
    for (int mf = 0; mf < 8; ++mf)
#pragma unroll
      for (int nf = 0; nf < 4; ++nf)
        acc[mf][nf] = __builtin_amdgcn_mfma_f32_16x16x32_bf16(af[mf], bfv[nf], acc[mf][nf], 0, 0, 0);
    if (pre) {
      asm volatile("s_waitcnt vmcnt(6)" ::: "memory");
    } else if (t + 1 < NK) {
      asm volatile("s_waitcnt vmcnt(0)" ::: "memory");
    }
    __builtin_amdgcn_sched_barrier(0);
    __builtin_amdgcn_s_barrier();
    ++cur; if (cur >= 3) cur -= 3;
  }
}

// -------- GEMM1: X @ Wcat^T with fused RoPE/sigmoid scatter epilogue --------
// 256x128 block (wave = 128x64). L2-aware XCD n-stripe: xcd owns 9 n-tiles
// (4.5 MB B), sweeps 16 m-tiles of 256 rows. V written TRANSPOSED to global.
__global__ __launch_bounds__(256, 2) void ga_gemm_qkvg(const unsigned short* __restrict__ A,
                                                       const unsigned short* __restrict__ Bt,
                                                       unsigned short* __restrict__ qo,
                                                       unsigned short* __restrict__ ko,
                                                       unsigned short* __restrict__ vo,
                                                       unsigned short* __restrict__ go) {
  __shared__ unsigned short As[3 * 256 * 32];
  __shared__ unsigned short Bs[3 * 128 * 32];
  int tid = threadIdx.x, lane = tid & 63, wid = tid >> 6;
  int wr = wid >> 1, wc = wid & 1;
  int lin = blockIdx.x;
  int xcd = lin & 7, j = lin >> 3;            // j in 0..143
  int n0 = (xcd * 9 + (j % 9)) * 128;         // n-tile 0..71 (stripe of 9/XCD)
  int m0 = (j / 9) * 256;                     // m-tile 0..15 (256 rows)
  f32x4 acc[8][4];
  f32x4 z = {0.f, 0.f, 0.f, 0.f};
#pragma unroll
  for (int i = 0; i < 8; ++i)
#pragma unroll
    for (int jj = 0; jj < 4; ++jj) acc[i][jj] = z;

  gemm_loop_256<EE>(A, Bt, As, Bs, m0, n0, acc);

  int li = lane & 15, lg = lane >> 4;
  int nb = n0 + wc * 64;      // 64-aligned col block (single region, single head)
  int mb = m0 + wr * 128;
  bool isq = nb < 4096;
  bool isk = (nb >= 4096) && (nb < 4608);
  bool isv = (nb >= 4608) && (nb < 5120);
  // ln(10000)/32
  float invf0 = expf((float)li * -0.2878231366242601f);
  float invf1 = expf((float)(16 + li) * -0.2878231366242601f);

#pragma unroll
  for (int mf = 0; mf < 8; ++mf) {
#pragma unroll
    for (int r = 0; r < 4; ++r) {
      int m = mb + mf * 16 + lg * 4 + r;
      int bb = m >> 11, s = m & 2047;
      if (isv) {
        // transposed V write: vt[(bb*HKV+hk)*DD + d][s]
        int hk = (nb - 4608) >> 8, hdb = (nb - 4608) & 255;
        unsigned short* dst = vo + ((size_t)(bb * HKV_ + hk) * DD + hdb) * SS + s;
#pragma unroll
        for (int nf = 0; nf < 4; ++nf)
          dst[(size_t)(nf * 16 + li) * SS] = f2bf(acc[mf][nf][r]);
      } else if (!isq && !isk) {  // gate: sigmoid
        int h = (nb - 5120) >> 8, hdb = (nb - 5120) & 255;
        unsigned short* dst = go + ((size_t)(bb * H_ + h) * SS + s) * DD + hdb;
#pragma unroll
        for (int nf = 0; nf < 4; ++nf) {
          float x = acc[mf][nf][r];
          dst[nf * 16 + li] = f2bf(1.f / (1.f + __expf(-x)));
        }
      } else {
        int hdb; unsigned short* dst;
        if (isq) { int h = nb >> 8; hdb = nb & 255;
                   dst = qo + ((size_t)(bb * H_ + h) * SS + s) * DD; }
        else     { int hk = (nb - 4096) >> 8; hdb = (nb - 4096) & 255;
                   dst = ko + ((size_t)(bb * HKV_ + hk) * SS + s) * DD; }
        if (hdb == 0) {
          // RoPE: hd = nf*16+li in [0,64); partner hd^32 is acc[mf][nf^2]
#pragma unroll
          for (int nf = 0; nf < 2; ++nf) {
            int fi = nf * 16 + li;
            float ang = (float)s * (nf ? invf1 : invf0);
            float sn, cs;
            sincosf(ang, &sn, &cs);
            float x1 = acc[mf][nf][r], x2 = acc[mf][nf + 2][r];
            dst[fi]      = f2bf(x1 * cs - x2 * sn);
            dst[fi + 32] = f2bf(x2 * cs + x1 * sn);
          }
        } else {
#pragma unroll
          for (int nf = 0; nf < 4; ++nf) dst[hdb + nf * 16 + li] = f2bf(acc[mf][nf][r]);
        }
      }
    }
  }
}

// -------- GEMM2: attn @ Wo^T -> fp32 out --------
// L2-aware XCD m-stripe mapping: xcd owns 4 contiguous m-tiles (A-stripe
// 4 MB ~ L2-resident), sweeps all 16 n-tiles with m inner.
__global__ __launch_bounds__(256) void ga_gemm_out(const unsigned short* __restrict__ A,
                                                   const unsigned short* __restrict__ Bt,
                                                   float* __restrict__ C) {
  __shared__ unsigned short As[3 * 128 * 32];
  __shared__ unsigned short Bs[3 * 128 * 32];
  int tid = threadIdx.x, lane = tid & 63, wid = tid >> 6;
  int wr = wid >> 1, wc = wid & 1;
  int lin = blockIdx.x;
  int xcd = lin & 7, j = lin >> 3;            // j in 0..63
  int m0 = (xcd * 4 + (j & 3)) * 128;         // m-tile 0..31 (stripe of 4/XCD)
  int n0 = (j >> 2) * 128;                    // n-tile 0..15
  f32x4 acc[4][4];
  f32x4 z = {0.f, 0.f, 0.f, 0.f};
#pragma unroll
  for (int i = 0; i < 4; ++i)
#pragma unroll
    for (int jj = 0; jj < 4; ++jj) acc[i][jj] = z;

  gemm_loop<HD>(A, Bt, As, Bs, m0, n0, acc);

  int li = lane & 15, lg = lane >> 4;
#pragma unroll
  for (int mf = 0; mf < 4; ++mf)
#pragma unroll
    for (int r = 0; r < 4; ++r) {
      int m = m0 + wr * 64 + mf * 16 + lg * 4 + r;
#pragma unroll
      for (int nf = 0; nf < 4; ++nf) {
        int n = n0 + wc * 64 + nf * 16 + li;
        C[(size_t)m * EE + n] = acc[mf][nf][r];
      }
    }
}

// ---- flash attention: swapped-QK 32x32 in-register softmax (m214 port) ----
// (unchanged from R13 — verified: XCD-local LPT dispatch, out of top-5)
__global__ __launch_bounds__(256) void ga_attn(const unsigned short* __restrict__ qb_,
                                               const unsigned short* __restrict__ kb,
                                               const unsigned short* __restrict__ vt,
                                               const unsigned short* __restrict__ gb,
                                               unsigned short* __restrict__ ob) {
  __shared__ unsigned short Ks[2][8192];   // [buf] 32 kv x 256 d (chunk-XOR row&7)
  __shared__ unsigned short Vs[2][8192];   // [buf] 256 d x 4 chunks (XOR d&3)
  __shared__ float Xch[4][32];             // per-wave scale broadcast
  int tid = threadIdx.x, lane = tid & 63, wid = tid >> 6;
  int col = lane & 31, hi = lane >> 5;
  int L = blockIdx.x;
  int xcd = L & 7, w = L >> 3;             // w in 0..63 within XCD
  int qblk = 15 - (w >> 2);                // LPT: heavy first, each qblk x4
  int bh = xcd * 4 + (w & 3);              // XCD-local heads (one (b,hk)/XCD)
  int q0 = qblk * 128;
  int b = bh >> 4, h = bh & 15, hk = h >> 3;
  const unsigned short* qp  = qb_ + ((size_t)(b * H_ + h) * SS) * DD;
  const unsigned short* kp  = kb + ((size_t)(b * HKV_ + hk) * SS) * DD;
  const unsigned short* vtp = vt + ((size_t)(b * HKV_ + hk) * DD) * SS;
  const unsigned short* gp  = gb + ((size_t)(b * H_ + h) * SS) * DD;

  // staging decode: 4 K-chunks + 4 V-chunks of 16B per thread per tile
  int kgo[4], vgo[4], lob[4];
#pragma unroll
  for (int it = 0; it < 4; ++it) {
    int c = it * 256 + tid;                          // chunk slot 0..1023
    int kr = c >> 5, c16 = c & 31;                   // K: 32 rows x 32 chunks
    kgo[it] = kr * DD + ((c16 ^ (kr & 7)) << 3);     // pre-swizzled source
    int vd = c >> 2;                                 // V: 256 rows x 4 chunks
    int cmg = (c & 3) ^ (vd & 3);
    vgo[it] = vd * SS + (cmg << 3);                  // 64B-coalesced source
    lob[it] = (it * 256 + wid * 64) * 8;             // wave-uniform LDS base
  }

  // Q fragments (B-operand): lane holds Q[q = qwave+col][d = ks*16 + hi*8 ..]
  int qwave = q0 + wid * 32;
  bf16x8 qf[16];
#pragma unroll
  for (int ks = 0; ks < 16; ++ks)
    qf[ks] = *(const bf16x8*)(qp + (size_t)(qwave + col) * DD + ks * 16 + hi * 8);

  f32x16 acc[8];
#pragma unroll
  for (int d8 = 0; d8 < 8; ++d8)
#pragma unroll
    for (int r = 0; r < 16; ++r) acc[d8][r] = 0.f;
  float mrun = -1e30f, lrun = 0.f;

  int nt = q0 / 32 + 4;
  int vs0 = ((hi) ^ (col & 3)) << 3;       // kstep0 chunk offset (elems)
  int vs1 = ((2 + hi) ^ (col & 3)) << 3;   // kstep1

  // prologue: stage tile 0 into buffer 0, wait, single barrier
#pragma unroll
  for (int it = 0; it < 4; ++it) {
    gll16(kp + kgo[it], &Ks[0][lob[it]]);
    gll16(vtp + vgo[it], &Vs[0][lob[it]]);
  }
  asm volatile("s_waitcnt vmcnt(0)" ::: "memory");
  __builtin_amdgcn_s_barrier();

  for (int t = 0; t < nt; ++t) {
    int kv0 = t * 32;
    int cur = t & 1;
    bool pre = (t + 1 < nt);
    if (pre) {
      int kvn = kv0 + 32;
#pragma unroll
      for (int it = 0; it < 4; ++it) {
        gll16(kp + (size_t)kvn * DD + kgo[it], &Ks[cur ^ 1][lob[it]]);
        gll16(vtp + kvn + vgo[it],             &Vs[cur ^ 1][lob[it]]);
      }
    }
    if (kv0 <= qwave + 31) {                  // wave-uniform causal activity
      // ---- swapped QK^T: S[kv][q] = mfma(A=K, B=Q) ----
      f32x16 sc;
#pragma unroll
      for (int r = 0; r < 16; ++r) sc[r] = 0.f;
      const unsigned short* kbase = &Ks[cur][col * 256];
      __builtin_amdgcn_s_setprio(1);
#pragma unroll
      for (int ks = 0; ks < 16; ++ks) {
        bf16x8 kfr = *(const bf16x8*)(kbase + (((ks * 2 + hi) ^ (col & 7)) << 3));
        sc = __builtin_amdgcn_mfma_f32_32x32x16_bf16(kfr, qf[ks], sc, 0, 0, 0);
      }
      __builtin_amdgcn_s_setprio(0);
      // ---- scale + causal mask (kv = crow(r,hi), q = col) ----
      bool needmask = (kv0 + 31 > qwave);
#pragma unroll
      for (int r = 0; r < 16; ++r) {
        int kvg = kv0 + (r & 3) + 8 * (r >> 2) + 4 * hi;
        float v = sc[r] * 0.0625f;
        if (needmask && kvg > qwave + col) v = -1e30f;
        sc[r] = v;
      }
      // ---- row max: in-lane tree + one partner exchange ----
      float pm = fmaxf(sc[0], sc[1]);
#pragma unroll
      for (int r = 2; r < 16; ++r) pm = fmaxf(pm, sc[r]);
      pm = fmaxf(pm, __shfl_xor(pm, 32));
      // ---- defer-max (THR=8); rare O-rescale via per-wave LDS broadcast ----
      if (!__all(pm - mrun <= 8.f)) {
        float nm = fmaxf(mrun, pm);
        float scl = __expf(mrun - nm);
        mrun = nm;
        lrun *= scl;
        if (lane < 32) Xch[wid][lane] = scl;
#pragma unroll
        for (int r = 0; r < 16; ++r) {
          float s2 = Xch[wid][(r & 3) + 8 * (r >> 2) + 4 * hi];
#pragma unroll
          for (int d8 = 0; d8 < 8; ++d8) acc[d8][r] *= s2;
        }
      }
      // ---- exp + sum (in-lane + one exchange) ----
      float rs = 0.f;
#pragma unroll
      for (int r = 0; r < 16; ++r) { float e = __expf(sc[r] - mrun); sc[r] = e; rs += e; }
      rs += __shfl_xor(rs, 32);
      lrun += rs;
      // ---- pack P to bf16 A-frags; one-hop exchanges across lane^32 ----
      unsigned w2[8];
#pragma unroll
      for (int jj = 0; jj < 8; ++jj)
        w2[jj] = ((unsigned)f2bf(sc[2 * jj + 1]) << 16) | (unsigned)f2bf(sc[2 * jj]);
      unsigned x0 = (unsigned)__shfl_xor((int)w2[2], 32);
      unsigned x1 = (unsigned)__shfl_xor((int)w2[3], 32);
      unsigned x2 = (unsigned)__shfl_xor((int)w2[0], 32);
      unsigned x3 = (unsigned)__shfl_xor((int)w2[1], 32);
      unsigned x4 = (unsigned)__shfl_xor((int)w2[6], 32);
      unsigned x5 = (unsigned)__shfl_xor((int)w2[7], 32);
      unsigned x6 = (unsigned)__shfl_xor((int)w2[4], 32);
      unsigned x7 = (unsigned)__shfl_xor((int)w2[5], 32);
      union { unsigned u[4]; bf16x8 v; } pa0, pa1;
      pa0.u[0] = hi ? x0 : w2[0];
      pa0.u[1] = hi ? x1 : w2[1];
      pa0.u[2] = hi ? w2[2] : x2;
      pa0.u[3] = hi ? w2[3] : x3;
      pa1.u[0] = hi ? x4 : w2[4];
      pa1.u[1] = hi ? x5 : w2[5];
      pa1.u[2] = hi ? w2[6] : x6;
      pa1.u[3] = hi ? w2[7] : x7;
      // ---- PV: O[q][d] += P @ V ----
      const unsigned short* vb = &Vs[cur][0];
      __builtin_amdgcn_s_setprio(1);
#pragma unroll
      for (int d8 = 0; d8 < 8; ++d8) {
        int rb = (d8 * 32 + col) * 32;
        bf16x8 bv0 = *(const bf16x8*)(vb + rb + vs0);
        bf16x8 bv1 = *(const bf16x8*)(vb + rb + vs1);
        acc[d8] = __builtin_amdgcn_mfma_f32_32x32x16_bf16(pa0.v, bv0, acc[d8], 0, 0, 0);
        acc[d8] = __builtin_amdgcn_mfma_f32_32x32x16_bf16(pa1.v, bv1, acc[d8], 0, 0, 0);
      }
      __builtin_amdgcn_s_setprio(0);
    }
    if (pre) {
      asm volatile("s_waitcnt vmcnt(0)" ::: "memory");   // next tile landed
    }
    __builtin_amdgcn_sched_barrier(0);
    __builtin_amdgcn_s_barrier();            // single barrier per tile
  }
  // ---- epilogue: normalize (broadcast 1/l), gate, store ----
  if (lane < 32) Xch[wid][lane] = 1.f / lrun;
#pragma unroll
  for (int r = 0; r < 16; ++r) {
    int crow = (r & 3) + 8 * (r >> 2) + 4 * hi;
    float inv2 = Xch[wid][crow];
    int qrow = qwave + crow;
    const unsigned short* gr = gp + (size_t)qrow * DD;
    unsigned short* orow = ob + ((size_t)(b * SS + qrow)) * HD + h * DD;
#pragma unroll
    for (int d8 = 0; d8 < 8; ++d8) {
      int d = d8 * 32 + col;
      float gv = bf2f(gr[d]);
      orow[d] = f2bf(acc[d8][r] * inv2 * gv);
    }
  }
}

extern "C" void kernel_launch(void* const* d_in, const int* in_sizes, int n_in,
                              void* d_out, int out_size, void* d_ws, size_t ws_size,
                              hipStream_t stream) {
  (void)in_sizes; (void)n_in; (void)out_size;
  const float* hs = (const float*)d_in[0];
  const float* Wq = (const float*)d_in[1];
  const float* Wk = (const float*)d_in[2];
  const float* Wv = (const float*)d_in[3];
  const float* Wg = (const float*)d_in[4];
  const float* Wo = (const float*)d_in[5];
  float* out = (float*)d_out;

  // workspace layout (bytes)
  const size_t off_X    = 0;                       // 4096x2048 bf16
  const size_t off_Wcat = off_X    + 16777216;     // 9216x2048 bf16 (transposed)
  const size_t off_Wot  = off_Wcat + 37748736;     // 2048x4096 bf16 (transposed)
  const size_t off_q    = off_Wot  + 16777216;     // B,H,S,D bf16
  const size_t off_k    = off_q    + 33554432;     // B,HKV,S,D
  const size_t off_v    = off_k    + 4194304;      // B,HKV,D,S (TRANSPOSED)
  const size_t off_g    = off_v    + 4194304;      // B,H,S,D
  const size_t off_attn = off_g    + 33554432;     // 4096x4096 bf16
  const size_t need     = off_attn + 33554432;     // ~172 MB
  if (ws_size < need) return;  // insufficient scratch: leave output poisoned

  char* ws = (char*)d_ws;
  unsigned short* Xbf   = (unsigned short*)(ws + off_X);
  unsigned short* Wcat  = (unsigned short*)(ws + off_Wcat);
  unsigned short* Wot   = (unsigned short*)(ws + off_Wot);
  unsigned short* qbf   = (unsigned short*)(ws + off_q);
  unsigned short* kbf   = (unsigned short*)(ws + off_k);
  unsigned short* vbf   = (unsigned short*)(ws + off_v);
  unsigned short* gbf   = (unsigned short*)(ws + off_g);
  unsigned short* attnb = (unsigned short*)(ws + off_attn);

  // 1) convert hidden_states to bf16
  ga_cvt<<<8192, 256, 0, stream>>>(hs, Xbf, MTOK * EE);
  // 2) pack weights (transposed, bf16)
  ga_pack_qkvg<<<dim3(144, 32), 256, 0, stream>>>(Wq, Wk, Wv, Wg, Wcat);
  ga_transpose_wo<<<dim3(32, 64), 256, 0, stream>>>(Wo, Wot, HD, EE);
  // 3) fused QKVG projection + RoPE + sigmoid (256x128 block, depth-2 vmcnt(6))
  ga_gemm_qkvg<<<dim3(1152), 256, 0, stream>>>(Xbf, Wcat, qbf, kbf, vbf, gbf);
  // 4) causal GQA flash attention + gating (XCD-local LPT dispatch)
  ga_attn<<<dim3(512), 256, 0, stream>>>(qbf, kbf, vbf, gbf, attnb);
  // 5) output projection (depth-2 + chunk-XOR swizzle, fp32 out)
  ga_gemm_out<<<dim3(512), 256, 0, stream>>>(attnb, Wot, out);
}

// Round 18
// 536.887 us; speedup vs baseline: 1.2268x; 1.2268x over previous
//
#include <hip/hip_runtime.h>
#include <hip/hip_bf16.h>
#include <cstdint>

typedef __attribute__((ext_vector_type(8))) short bf16x8;
typedef __attribute__((ext_vector_type(4))) float f32x4;
typedef __attribute__((ext_vector_type(16))) float f32x16;

#define H_   16
#define HKV_ 2
#define DD   256
#define BB   2
#define SS   2048
#define EE   2048
#define MTOK (BB*SS)     // 4096
#define HD   (H_*DD)     // 4096

static __device__ __forceinline__ unsigned short f2bf(float f) {
  union { float f; unsigned u; } v; v.f = f;
  unsigned r = v.u + 0x7fffu + ((v.u >> 16) & 1u);
  return (unsigned short)(r >> 16);
}
static __device__ __forceinline__ float bf2f(unsigned short h) {
  union { unsigned u; float f; } v; v.u = ((unsigned)h) << 16;
  return v.f;
}

static __device__ __forceinline__ void gll16(const unsigned short* g, unsigned short* l) {
  __builtin_amdgcn_global_load_lds(
      (const __attribute__((address_space(1))) unsigned int*)g,
      (__attribute__((address_space(3))) unsigned int*)l, 16, 0, 0);
}

// ---------------- fp32 -> bf16 convert (vectorized) ----------------
__global__ __launch_bounds__(256) void ga_cvt(const float* __restrict__ in,
                                              unsigned short* __restrict__ out, int n) {
  int i = (blockIdx.x * 256 + threadIdx.x) * 4;
  if (i >= n) return;
  float4 v = *(const float4*)(in + i);
  ushort4 o;
  o.x = f2bf(v.x); o.y = f2bf(v.y); o.z = f2bf(v.z); o.w = f2bf(v.w);
  *(ushort4*)(out + i) = o;
}

// -------- transpose+convert: out[c][r] = bf16(in[r][c]), in is R x C --------
__global__ __launch_bounds__(256) void ga_transpose_wo(const float* __restrict__ in,
                                                       unsigned short* __restrict__ out,
                                                       int R, int C) {
  __shared__ float tile[64][65];
  int c0 = blockIdx.x * 64, r0 = blockIdx.y * 64;
  int tid = threadIdx.x;
#pragma unroll
  for (int it = 0; it < 16; ++it) {
    int idx = it * 256 + tid; int rr = idx >> 6, cc = idx & 63;
    tile[rr][cc] = in[(size_t)(r0 + rr) * C + c0 + cc];
  }
  __syncthreads();
#pragma unroll
  for (int it = 0; it < 16; ++it) {
    int idx = it * 256 + tid; int rr = idx >> 6, cc = idx & 63;
    out[(size_t)(c0 + rr) * R + r0 + cc] = f2bf(tile[cc][rr]);
  }
}

// -------- pack [Wq|Wk|Wv|Wg] transposed: out[n][k], n in [0,9216) --------
__global__ __launch_bounds__(256) void ga_pack_qkvg(const float* __restrict__ Wq,
                                                    const float* __restrict__ Wk,
                                                    const float* __restrict__ Wv,
                                                    const float* __restrict__ Wg,
                                                    unsigned short* __restrict__ out) {
  __shared__ float tile[64][65];
  int n0 = blockIdx.x * 64, k0 = blockIdx.y * 64;
  const float* src; int C, cbase;
  if (n0 < 4096)      { src = Wq; C = 4096; cbase = n0; }
  else if (n0 < 4608) { src = Wk; C = 512;  cbase = n0 - 4096; }
  else if (n0 < 5120) { src = Wv; C = 512;  cbase = n0 - 4608; }
  else                { src = Wg; C = 4096; cbase = n0 - 5120; }
  int tid = threadIdx.x;
#pragma unroll
  for (int it = 0; it < 16; ++it) {
    int idx = it * 256 + tid; int rr = idx >> 6, cc = idx & 63;
    tile[rr][cc] = src[(size_t)(k0 + rr) * C + cbase + cc];
  }
  __syncthreads();
#pragma unroll
  for (int it = 0; it < 16; ++it) {
    int idx = it * 256 + tid; int rr = idx >> 6, cc = idx & 63;
    out[(size_t)(n0 + rr) * EE + k0 + cc] = f2bf(tile[cc][rr]);
  }
}

// ---- shared 128x128 GEMM main loop, TRIPLE-BUFFERED depth-2 prefetch ----
// T4 counted vmcnt + T2 chunk-XOR swizzle (both-sides, row bits 2-3).
// Verified R16: LDS[row][cs] holds G[row][cs ^ ((row>>2)&3)] via pre-swizzled
// global source (LDS dest linear); frag read chunk = lg ^ ((li>>2)&3).
// As/Bs are [3][128*32] element arrays.
template<int KDIM>
static __device__ __forceinline__ void gemm_loop(const unsigned short* __restrict__ A,
                                                 const unsigned short* __restrict__ Bt,
                                                 unsigned short* As, unsigned short* Bs,
                                                 int m0, int n0, f32x4 acc[4][4]) {
  int tid = threadIdx.x, lane = tid & 63, wid = tid >> 6;
  int wr = wid >> 1, wc = wid & 1;
  int li = lane & 15, lg = lane >> 4;
  int xsw = (li >> 2) & 3;                  // lane-constant read-side XOR
  int rowA[2], cb8[2], ldso[2];
#pragma unroll
  for (int r2 = 0; r2 < 2; ++r2) {
    int c = r2 * 256 + wid * 64 + lane;
    rowA[r2] = c >> 2;
    cb8[r2] = (((c & 3) ^ ((c >> 4) & 3)) * 8);
    ldso[r2] = (r2 * 256 + wid * 64) * 8;   // wave-uniform LDS base (elems)
  }
#pragma unroll
  for (int p = 0; p < 2; ++p) {
#pragma unroll
    for (int r2 = 0; r2 < 2; ++r2) {
      gll16(A  + (size_t)(m0 + rowA[r2]) * KDIM + p * 32 + cb8[r2], As + p * 4096 + ldso[r2]);
      gll16(Bt + (size_t)(n0 + rowA[r2]) * KDIM + p * 32 + cb8[r2], Bs + p * 4096 + ldso[r2]);
    }
  }
  asm volatile("s_waitcnt vmcnt(4)" ::: "memory");   // batch 0 landed
  __builtin_amdgcn_s_barrier();

  const int NK = KDIM / 32;
  int cur = 0;
  for (int t = 0; t < NK; ++t) {
    unsigned short* Asc = As + cur * 4096;
    unsigned short* Bsc = Bs + cur * 4096;
    bool pre = (t + 2 < NK);
    if (pre) {
      int k0 = (t + 2) * 32;
      int wbuf = cur + 2; if (wbuf >= 3) wbuf -= 3;
      unsigned short* Asn = As + wbuf * 4096;
      unsigned short* Bsn = Bs + wbuf * 4096;
#pragma unroll
      for (int r2 = 0; r2 < 2; ++r2) {
        gll16(A  + (size_t)(m0 + rowA[r2]) * KDIM + k0 + cb8[r2], Asn + ldso[r2]);
        gll16(Bt + (size_t)(n0 + rowA[r2]) * KDIM + k0 + cb8[r2], Bsn + ldso[r2]);
      }
    }
    bf16x8 af[4], bfv[4];
#pragma unroll
    for (int mf = 0; mf < 4; ++mf)
      af[mf] = *(const bf16x8*)&Asc[(wr * 64 + mf * 16 + li) * 32 + ((lg ^ xsw) << 3)];
#pragma unroll
    for (int nf = 0; nf < 4; ++nf)
      bfv[nf] = *(const bf16x8*)&Bsc[(wc * 64 + nf * 16 + li) * 32 + ((lg ^ xsw) << 3)];
#pragma unroll
    for (int mf = 0; mf < 4; ++mf)
#pragma unroll
      for (int nf = 0; nf < 4; ++nf)
        acc[mf][nf] = __builtin_amdgcn_mfma_f32_16x16x32_bf16(af[mf], bfv[nf], acc[mf][nf], 0, 0, 0);
    if (pre) {
      asm volatile("s_waitcnt vmcnt(4)" ::: "memory");
    } else if (t + 1 < NK) {
      asm volatile("s_waitcnt vmcnt(0)" ::: "memory");
    }
    __builtin_amdgcn_sched_barrier(0);
    __builtin_amdgcn_s_barrier();
    ++cur; if (cur >= 3) cur -= 3;
  }
}

// -------- GEMM1: X @ Wcat^T with fused RoPE/sigmoid scatter epilogue --------
// (reverted to R16-verified 128x128 form; R17's 256x128 spilled acc to scratch)
// L2-aware XCD n-stripe mapping: xcd = lin&7 owns 9 contiguous n-tiles
// (B-stripe 4.5 MB ~ L2-resident), sweeps all 32 m-tiles with n inner.
// V is written TRANSPOSED to global: vt[b][hk][d][s]  (enables plain-load PV)
__global__ __launch_bounds__(256) void ga_gemm_qkvg(const unsigned short* __restrict__ A,
                                                    const unsigned short* __restrict__ Bt,
                                                    unsigned short* __restrict__ qo,
                                                    unsigned short* __restrict__ ko,
                                                    unsigned short* __restrict__ vo,
                                                    unsigned short* __restrict__ go) {
  __shared__ unsigned short As[3 * 128 * 32];
  __shared__ unsigned short Bs[3 * 128 * 32];
  int tid = threadIdx.x, lane = tid & 63, wid = tid >> 6;
  int wr = wid >> 1, wc = wid & 1;
  int lin = blockIdx.x;
  int xcd = lin & 7, j = lin >> 3;            // j in 0..287
  int n0 = (xcd * 9 + (j % 9)) * 128;         // n-tile 0..71 (stripe of 9/XCD)
  int m0 = (j / 9) * 128;                     // m-tile 0..31
  f32x4 acc[4][4];
  f32x4 z = {0.f, 0.f, 0.f, 0.f};
#pragma unroll
  for (int i = 0; i < 4; ++i)
#pragma unroll
    for (int jj = 0; jj < 4; ++jj) acc[i][jj] = z;

  gemm_loop<EE>(A, Bt, As, Bs, m0, n0, acc);

  int li = lane & 15, lg = lane >> 4;
  int nb = n0 + wc * 64;      // 64-aligned col block (single region, single head)
  int mb = m0 + wr * 64;
  bool isq = nb < 4096;
  bool isk = (nb >= 4096) && (nb < 4608);
  bool isv = (nb >= 4608) && (nb < 5120);
  // ln(10000)/32
  float invf0 = expf((float)li * -0.2878231366242601f);
  float invf1 = expf((float)(16 + li) * -0.2878231366242601f);

#pragma unroll
  for (int mf = 0; mf < 4; ++mf) {
#pragma unroll
    for (int r = 0; r < 4; ++r) {
      int m = mb + mf * 16 + lg * 4 + r;
      int bb = m >> 11, s = m & 2047;
      if (isv) {
        // transposed V write: vt[(bb*HKV+hk)*DD + d][s]
        int hk = (nb - 4608) >> 8, hdb = (nb - 4608) & 255;
        unsigned short* dst = vo + ((size_t)(bb * HKV_ + hk) * DD + hdb) * SS + s;
#pragma unroll
        for (int nf = 0; nf < 4; ++nf)
          dst[(size_t)(nf * 16 + li) * SS] = f2bf(acc[mf][nf][r]);
      } else if (!isq && !isk) {  // gate: sigmoid
        int h = (nb - 5120) >> 8, hdb = (nb - 5120) & 255;
        unsigned short* dst = go + ((size_t)(bb * H_ + h) * SS + s) * DD + hdb;
#pragma unroll
        for (int nf = 0; nf < 4; ++nf) {
          float x = acc[mf][nf][r];
          dst[nf * 16 + li] = f2bf(1.f / (1.f + __expf(-x)));
        }
      } else {
        int hdb; unsigned short* dst;
        if (isq) { int h = nb >> 8; hdb = nb & 255;
                   dst = qo + ((size_t)(bb * H_ + h) * SS + s) * DD; }
        else     { int hk = (nb - 4096) >> 8; hdb = (nb - 4096) & 255;
                   dst = ko + ((size_t)(bb * HKV_ + hk) * SS + s) * DD; }
        if (hdb == 0) {
          // RoPE: hd = nf*16+li in [0,64); partner hd^32 is acc[mf][nf^2]
#pragma unroll
          for (int nf = 0; nf < 2; ++nf) {
            int fi = nf * 16 + li;
            float ang = (float)s * (nf ? invf1 : invf0);
            float sn, cs;
            sincosf(ang, &sn, &cs);
            float x1 = acc[mf][nf][r], x2 = acc[mf][nf + 2][r];
            dst[fi]      = f2bf(x1 * cs - x2 * sn);
            dst[fi + 32] = f2bf(x2 * cs + x1 * sn);
          }
        } else {
#pragma unroll
          for (int nf = 0; nf < 4; ++nf) dst[hdb + nf * 16 + li] = f2bf(acc[mf][nf][r]);
        }
      }
    }
  }
}

// -------- GEMM2: attn @ Wo^T -> fp32 out --------
// L2-aware XCD m-stripe mapping: xcd owns 4 contiguous m-tiles (A-stripe
// 4 MB ~ L2-resident), sweeps all 16 n-tiles with m inner.
__global__ __launch_bounds__(256) void ga_gemm_out(const unsigned short* __restrict__ A,
                                                   const unsigned short* __restrict__ Bt,
                                                   float* __restrict__ C) {
  __shared__ unsigned short As[3 * 128 * 32];
  __shared__ unsigned short Bs[3 * 128 * 32];
  int tid = threadIdx.x, lane = tid & 63, wid = tid >> 6;
  int wr = wid >> 1, wc = wid & 1;
  int lin = blockIdx.x;
  int xcd = lin & 7, j = lin >> 3;            // j in 0..63
  int m0 = (xcd * 4 + (j & 3)) * 128;         // m-tile 0..31 (stripe of 4/XCD)
  int n0 = (j >> 2) * 128;                    // n-tile 0..15
  f32x4 acc[4][4];
  f32x4 z = {0.f, 0.f, 0.f, 0.f};
#pragma unroll
  for (int i = 0; i < 4; ++i)
#pragma unroll
    for (int jj = 0; jj < 4; ++jj) acc[i][jj] = z;

  gemm_loop<HD>(A, Bt, As, Bs, m0, n0, acc);

  int li = lane & 15, lg = lane >> 4;
#pragma unroll
  for (int mf = 0; mf < 4; ++mf)
#pragma unroll
    for (int r = 0; r < 4; ++r) {
      int m = m0 + wr * 64 + mf * 16 + lg * 4 + r;
#pragma unroll
      for (int nf = 0; nf < 4; ++nf) {
        int n = n0 + wc * 64 + nf * 16 + li;
        C[(size_t)m * EE + n] = acc[mf][nf][r];
      }
    }
}

// ---- flash attention: swapped-QK 32x32 in-register softmax (m214 port) ----
// (unchanged from R13 — verified: XCD-local LPT dispatch, out of top-5)
__global__ __launch_bounds__(256) void ga_attn(const unsigned short* __restrict__ qb_,
                                               const unsigned short* __restrict__ kb,
                                               const unsigned short* __restrict__ vt,
                                               const unsigned short* __restrict__ gb,
                                               unsigned short* __restrict__ ob) {
  __shared__ unsigned short Ks[2][8192];   // [buf] 32 kv x 256 d (chunk-XOR row&7)
  __shared__ unsigned short Vs[2][8192];   // [buf] 256 d x 4 chunks (XOR d&3)
  __shared__ float Xch[4][32];             // per-wave scale broadcast
  int tid = threadIdx.x, lane = tid & 63, wid = tid >> 6;
  int col = lane & 31, hi = lane >> 5;
  int L = blockIdx.x;
  int xcd = L & 7, w = L >> 3;             // w in 0..63 within XCD
  int qblk = 15 - (w >> 2);                // LPT: heavy first, each qblk x4
  int bh = xcd * 4 + (w & 3);              // XCD-local heads (one (b,hk)/XCD)
  int q0 = qblk * 128;
  int b = bh >> 4, h = bh & 15, hk = h >> 3;
  const unsigned short* qp  = qb_ + ((size_t)(b * H_ + h) * SS) * DD;
  const unsigned short* kp  = kb + ((size_t)(b * HKV_ + hk) * SS) * DD;
  const unsigned short* vtp = vt + ((size_t)(b * HKV_ + hk) * DD) * SS;
  const unsigned short* gp  = gb + ((size_t)(b * H_ + h) * SS) * DD;

  // staging decode: 4 K-chunks + 4 V-chunks of 16B per thread per tile
  int kgo[4], vgo[4], lob[4];
#pragma unroll
  for (int it = 0; it < 4; ++it) {
    int c = it * 256 + tid;                          // chunk slot 0..1023
    int kr = c >> 5, c16 = c & 31;                   // K: 32 rows x 32 chunks
    kgo[it] = kr * DD + ((c16 ^ (kr & 7)) << 3);     // pre-swizzled source
    int vd = c >> 2;                                 // V: 256 rows x 4 chunks
    int cmg = (c & 3) ^ (vd & 3);
    vgo[it] = vd * SS + (cmg << 3);                  // 64B-coalesced source
    lob[it] = (it * 256 + wid * 64) * 8;             // wave-uniform LDS base
  }

  // Q fragments (B-operand): lane holds Q[q = qwave+col][d = ks*16 + hi*8 ..]
  int qwave = q0 + wid * 32;
  bf16x8 qf[16];
#pragma unroll
  for (int ks = 0; ks < 16; ++ks)
    qf[ks] = *(const bf16x8*)(qp + (size_t)(qwave + col) * DD + ks * 16 + hi * 8);

  f32x16 acc[8];
#pragma unroll
  for (int d8 = 0; d8 < 8; ++d8)
#pragma unroll
    for (int r = 0; r < 16; ++r) acc[d8][r] = 0.f;
  float mrun = -1e30f, lrun = 0.f;

  int nt = q0 / 32 + 4;
  int vs0 = ((hi) ^ (col & 3)) << 3;       // kstep0 chunk offset (elems)
  int vs1 = ((2 + hi) ^ (col & 3)) << 3;   // kstep1

  // prologue: stage tile 0 into buffer 0, wait, single barrier
#pragma unroll
  for (int it = 0; it < 4; ++it) {
    gll16(kp + kgo[it], &Ks[0][lob[it]]);
    gll16(vtp + vgo[it], &Vs[0][lob[it]]);
  }
  asm volatile("s_waitcnt vmcnt(0)" ::: "memory");
  __builtin_amdgcn_s_barrier();

  for (int t = 0; t < nt; ++t) {
    int kv0 = t * 32;
    int cur = t & 1;
    bool pre = (t + 1 < nt);
    if (pre) {
      int kvn = kv0 + 32;
#pragma unroll
      for (int it = 0; it < 4; ++it) {
        gll16(kp + (size_t)kvn * DD + kgo[it], &Ks[cur ^ 1][lob[it]]);
        gll16(vtp + kvn + vgo[it],             &Vs[cur ^ 1][lob[it]]);
      }
    }
    if (kv0 <= qwave + 31) {                  // wave-uniform causal activity
      // ---- swapped QK^T: S[kv][q] = mfma(A=K, B=Q) ----
      f32x16 sc;
#pragma unroll
      for (int r = 0; r < 16; ++r) sc[r] = 0.f;
      const unsigned short* kbase = &Ks[cur][col * 256];
      __builtin_amdgcn_s_setprio(1);
#pragma unroll
      for (int ks = 0; ks < 16; ++ks) {
        bf16x8 kfr = *(const bf16x8*)(kbase + (((ks * 2 + hi) ^ (col & 7)) << 3));
        sc = __builtin_amdgcn_mfma_f32_32x32x16_bf16(kfr, qf[ks], sc, 0, 0, 0);
      }
      __builtin_amdgcn_s_setprio(0);
      // ---- scale + causal mask (kv = crow(r,hi), q = col) ----
      bool needmask = (kv0 + 31 > qwave);
#pragma unroll
      for (int r = 0; r < 16; ++r) {
        int kvg = kv0 + (r & 3) + 8 * (r >> 2) + 4 * hi;
        float v = sc[r] * 0.0625f;
        if (needmask && kvg > qwave + col) v = -1e30f;
        sc[r] = v;
      }
      // ---- row max: in-lane tree + one partner exchange ----
      float pm = fmaxf(sc[0], sc[1]);
#pragma unroll
      for (int r = 2; r < 16; ++r) pm = fmaxf(pm, sc[r]);
      pm = fmaxf(pm, __shfl_xor(pm, 32));
      // ---- defer-max (THR=8); rare O-rescale via per-wave LDS broadcast ----
      if (!__all(pm - mrun <= 8.f)) {
        float nm = fmaxf(mrun, pm);
        float scl = __expf(mrun - nm);
        mrun = nm;
        lrun *= scl;
        if (lane < 32) Xch[wid][lane] = scl;
#pragma unroll
        for (int r = 0; r < 16; ++r) {
          float s2 = Xch[wid][(r & 3) + 8 * (r >> 2) + 4 * hi];
#pragma unroll
          for (int d8 = 0; d8 < 8; ++d8) acc[d8][r] *= s2;
        }
      }
      // ---- exp + sum (in-lane + one exchange) ----
      float rs = 0.f;
#pragma unroll
      for (int r = 0; r < 16; ++r) { float e = __expf(sc[r] - mrun); sc[r] = e; rs += e; }
      rs += __shfl_xor(rs, 32);
      lrun += rs;
      // ---- pack P to bf16 A-frags; one-hop exchanges across lane^32 ----
      unsigned w2[8];
#pragma unroll
      for (int jj = 0; jj < 8; ++jj)
        w2[jj] = ((unsigned)f2bf(sc[2 * jj + 1]) << 16) | (unsigned)f2bf(sc[2 * jj]);
      unsigned x0 = (unsigned)__shfl_xor((int)w2[2], 32);
      unsigned x1 = (unsigned)__shfl_xor((int)w2[3], 32);
      unsigned x2 = (unsigned)__shfl_xor((int)w2[0], 32);
      unsigned x3 = (unsigned)__shfl_xor((int)w2[1], 32);
      unsigned x4 = (unsigned)__shfl_xor((int)w2[6], 32);
      unsigned x5 = (unsigned)__shfl_xor((int)w2[7], 32);
      unsigned x6 = (unsigned)__shfl_xor((int)w2[4], 32);
      unsigned x7 = (unsigned)__shfl_xor((int)w2[5], 32);
      union { unsigned u[4]; bf16x8 v; } pa0, pa1;
      pa0.u[0] = hi ? x0 : w2[0];
      pa0.u[1] = hi ? x1 : w2[1];
      pa0.u[2] = hi ? w2[2] : x2;
      pa0.u[3] = hi ? w2[3] : x3;
      pa1.u[0] = hi ? x4 : w2[4];
      pa1.u[1] = hi ? x5 : w2[5];
      pa1.u[2] = hi ? w2[6] : x6;
      pa1.u[3] = hi ? w2[7] : x7;
      // ---- PV: O[q][d] += P @ V ----
      const unsigned short* vb = &Vs[cur][0];
      __builtin_amdgcn_s_setprio(1);
#pragma unroll
      for (int d8 = 0; d8 < 8; ++d8) {
        int rb = (d8 * 32 + col) * 32;
        bf16x8 bv0 = *(const bf16x8*)(vb + rb + vs0);
        bf16x8 bv1 = *(const bf16x8*)(vb + rb + vs1);
        acc[d8] = __builtin_amdgcn_mfma_f32_32x32x16_bf16(pa0.v, bv0, acc[d8], 0, 0, 0);
        acc[d8] = __builtin_amdgcn_mfma_f32_32x32x16_bf16(pa1.v, bv1, acc[d8], 0, 0, 0);
      }
      __builtin_amdgcn_s_setprio(0);
    }
    if (pre) {
      asm volatile("s_waitcnt vmcnt(0)" ::: "memory");   // next tile landed
    }
    __builtin_amdgcn_sched_barrier(0);
    __builtin_amdgcn_s_barrier();            // single barrier per tile
  }
  // ---- epilogue: normalize (broadcast 1/l), gate, store ----
  if (lane < 32) Xch[wid][lane] = 1.f / lrun;
#pragma unroll
  for (int r = 0; r < 16; ++r) {
    int crow = (r & 3) + 8 * (r >> 2) + 4 * hi;
    float inv2 = Xch[wid][crow];
    int qrow = qwave + crow;
    const unsigned short* gr = gp + (size_t)qrow * DD;
    unsigned short* orow = ob + ((size_t)(b * SS + qrow)) * HD + h * DD;
#pragma unroll
    for (int d8 = 0; d8 < 8; ++d8) {
      int d = d8 * 32 + col;
      float gv = bf2f(gr[d]);
      orow[d] = f2bf(acc[d8][r] * inv2 * gv);
    }
  }
}

extern "C" void kernel_launch(void* const* d_in, const int* in_sizes, int n_in,
                              void* d_out, int out_size, void* d_ws, size_t ws_size,
                              hipStream_t stream) {
  (void)in_sizes; (void)n_in; (void)out_size;
  const float* hs = (const float*)d_in[0];
  const float* Wq = (const float*)d_in[1];
  const float* Wk = (const float*)d_in[2];
  const float* Wv = (const float*)d_in[3];
  const float* Wg = (const float*)d_in[4];
  const float* Wo = (const float*)d_in[5];
  float* out = (float*)d_out;

  // workspace layout (bytes)
  const size_t off_X    = 0;                       // 4096x2048 bf16
  const size_t off_Wcat = off_X    + 16777216;     // 9216x2048 bf16 (transposed)
  const size_t off_Wot  = off_Wcat + 37748736;     // 2048x4096 bf16 (transposed)
  const size_t off_q    = off_Wot  + 16777216;     // B,H,S,D bf16
  const size_t off_k    = off_q    + 33554432;     // B,HKV,S,D
  const size_t off_v    = off_k    + 4194304;      // B,HKV,D,S (TRANSPOSED)
  const size_t off_g    = off_v    + 4194304;      // B,H,S,D
  const size_t off_attn = off_g    + 33554432;     // 4096x4096 bf16
  const size_t need     = off_attn + 33554432;     // ~172 MB
  if (ws_size < need) return;  // insufficient scratch: leave output poisoned

  char* ws = (char*)d_ws;
  unsigned short* Xbf   = (unsigned short*)(ws + off_X);
  unsigned short* Wcat  = (unsigned short*)(ws + off_Wcat);
  unsigned short* Wot   = (unsigned short*)(ws + off_Wot);
  unsigned short* qbf   = (unsigned short*)(ws + off_q);
  unsigned short* kbf   = (unsigned short*)(ws + off_k);
  unsigned short* vbf   = (unsigned short*)(ws + off_v);
  unsigned short* gbf   = (unsigned short*)(ws + off_g);
  unsigned short* attnb = (unsigned short*)(ws + off_attn);

  // 1) convert hidden_states to bf16
  ga_cvt<<<8192, 256, 0, stream>>>(hs, Xbf, MTOK * EE);
  // 2) pack weights (transposed, bf16)
  ga_pack_qkvg<<<dim3(144, 32), 256, 0, stream>>>(Wq, Wk, Wv, Wg, Wcat);
  ga_transpose_wo<<<dim3(32, 64), 256, 0, stream>>>(Wo, Wot, HD, EE);
  // 3) fused QKVG projection + RoPE + sigmoid (depth-2 + chunk-XOR swizzle)
  ga_gemm_qkvg<<<dim3(2304), 256, 0, stream>>>(Xbf, Wcat, qbf, kbf, vbf, gbf);
  // 4) causal GQA flash attention + gating (XCD-local LPT dispatch)
  ga_attn<<<dim3(512), 256, 0, stream>>>(qbf, kbf, vbf, gbf, attnb);
  // 5) output projection (depth-2 + chunk-XOR swizzle, fp32 out)
  ga_gemm_out<<<dim3(512), 256, 0, stream>>>(attnb, Wot, out);
}

// Round 19
// 517.972 us; speedup vs baseline: 1.2716x; 1.0365x over previous
//
#include <hip/hip_runtime.h>
#include <hip/hip_bf16.h>
#include <cstdint>

typedef __attribute__((ext_vector_type(8))) short bf16x8;
typedef __attribute__((ext_vector_type(4))) float f32x4;
typedef __attribute__((ext_vector_type(16))) float f32x16;

#define H_   16
#define HKV_ 2
#define DD   256
#define BB   2
#define SS   2048
#define EE   2048
#define MTOK (BB*SS)     // 4096
#define HD   (H_*DD)     // 4096

static __device__ __forceinline__ unsigned short f2bf(float f) {
  union { float f; unsigned u; } v; v.f = f;
  unsigned r = v.u + 0x7fffu + ((v.u >> 16) & 1u);
  return (unsigned short)(r >> 16);
}
static __device__ __forceinline__ float bf2f(unsigned short h) {
  union { unsigned u; float f; } v; v.u = ((unsigned)h) << 16;
  return v.f;
}

static __device__ __forceinline__ void gll16(const unsigned short* g, unsigned short* l) {
  __builtin_amdgcn_global_load_lds(
      (const __attribute__((address_space(1))) unsigned int*)g,
      (__attribute__((address_space(3))) unsigned int*)l, 16, 0, 0);
}

// ---------------- fp32 -> bf16 convert (vectorized) ----------------
__global__ __launch_bounds__(256) void ga_cvt(const float* __restrict__ in,
                                              unsigned short* __restrict__ out, int n) {
  int i = (blockIdx.x * 256 + threadIdx.x) * 4;
  if (i >= n) return;
  float4 v = *(const float4*)(in + i);
  ushort4 o;
  o.x = f2bf(v.x); o.y = f2bf(v.y); o.z = f2bf(v.z); o.w = f2bf(v.w);
  *(ushort4*)(out + i) = o;
}

// -------- transpose+convert: out[c][r] = bf16(in[r][c]), in is R x C --------
__global__ __launch_bounds__(256) void ga_transpose_wo(const float* __restrict__ in,
                                                       unsigned short* __restrict__ out,
                                                       int R, int C) {
  __shared__ float tile[64][65];
  int c0 = blockIdx.x * 64, r0 = blockIdx.y * 64;
  int tid = threadIdx.x;
#pragma unroll
  for (int it = 0; it < 16; ++it) {
    int idx = it * 256 + tid; int rr = idx >> 6, cc = idx & 63;
    tile[rr][cc] = in[(size_t)(r0 + rr) * C + c0 + cc];
  }
  __syncthreads();
#pragma unroll
  for (int it = 0; it < 16; ++it) {
    int idx = it * 256 + tid; int rr = idx >> 6, cc = idx & 63;
    out[(size_t)(c0 + rr) * R + r0 + cc] = f2bf(tile[cc][rr]);
  }
}

// -------- pack [Wq|Wk|Wv|Wg] transposed: out[n][k], n in [0,9216) --------
__global__ __launch_bounds__(256) void ga_pack_qkvg(const float* __restrict__ Wq,
                                                    const float* __restrict__ Wk,
                                                    const float* __restrict__ Wv,
                                                    const float* __restrict__ Wg,
                                                    unsigned short* __restrict__ out) {
  __shared__ float tile[64][65];
  int n0 = blockIdx.x * 64, k0 = blockIdx.y * 64;
  const float* src; int C, cbase;
  if (n0 < 4096)      { src = Wq; C = 4096; cbase = n0; }
  else if (n0 < 4608) { src = Wk; C = 512;  cbase = n0 - 4096; }
  else if (n0 < 5120) { src = Wv; C = 512;  cbase = n0 - 4608; }
  else                { src = Wg; C = 4096; cbase = n0 - 5120; }
  int tid = threadIdx.x;
#pragma unroll
  for (int it = 0; it < 16; ++it) {
    int idx = it * 256 + tid; int rr = idx >> 6, cc = idx & 63;
    tile[rr][cc] = src[(size_t)(k0 + rr) * C + cbase + cc];
  }
  __syncthreads();
#pragma unroll
  for (int it = 0; it < 16; ++it) {
    int idx = it * 256 + tid; int rr = idx >> 6, cc = idx & 63;
    out[(size_t)(n0 + rr) * EE + k0 + cc] = f2bf(tile[cc][rr]);
  }
}

// ---- shared 128x128 GEMM main loop, BK=64, DOUBLE-BUFFERED depth-1 ----
// 32 barriers instead of 64; each prefetch batch has a full BK=64 compute
// phase (~2x longer) to land. LDS 64KB total -> 2 blocks/CU (unchanged).
// Swizzle (both-sides rule #21) for 64-elem (128B) rows: LDS[row][cs] holds
// G[row][cs ^ (row&7)] via pre-swizzled global source (LDS dest linear);
// frag read chunk = (kh*4+lg) ^ (li&7) -> banks spread 8x4, 2-way, free.
// As/Bs are [2][128*64] element arrays.
template<int KDIM>
static __device__ __forceinline__ void gemm_loop64(const unsigned short* __restrict__ A,
                                                   const unsigned short* __restrict__ Bt,
                                                   unsigned short* As, unsigned short* Bs,
                                                   int m0, int n0, f32x4 acc[4][4]) {
  int tid = threadIdx.x, lane = tid & 63, wid = tid >> 6;
  int wr = wid >> 1, wc = wid & 1;
  int li = lane & 15, lg = lane >> 4;
  int x7 = li & 7;                            // lane-constant read-side XOR
  // staging decode: 4 chunks of 16B per thread per array (128x64 tile)
  int rowX[4], cbX[4], ldso[4];
#pragma unroll
  for (int it = 0; it < 4; ++it) {
    int c = it * 256 + tid;                   // chunk 0..1023
    int row = c >> 3, cs = c & 7;             // 128 rows x 8 chunks
    rowX[it] = row;
    cbX[it] = ((cs ^ (row & 7)) << 3);        // pre-swizzled source (elems)
    ldso[it] = (it * 256 + wid * 64) * 8;     // wave-uniform LDS base (elems)
  }
  // prologue: stage K-step 0 into buffer 0
#pragma unroll
  for (int it = 0; it < 4; ++it) {
    gll16(A  + (size_t)(m0 + rowX[it]) * KDIM + cbX[it], As + ldso[it]);
    gll16(Bt + (size_t)(n0 + rowX[it]) * KDIM + cbX[it], Bs + ldso[it]);
  }
  asm volatile("s_waitcnt vmcnt(0)" ::: "memory");
  __builtin_amdgcn_s_barrier();

  const int NK = KDIM / 64;
  for (int t = 0; t < NK; ++t) {
    int cur = t & 1;
    unsigned short* Asc = As + cur * 8192;
    unsigned short* Bsc = Bs + cur * 8192;
    bool pre = (t + 1 < NK);
    if (pre) {
      int k0 = (t + 1) * 64;
      unsigned short* Asn = As + (cur ^ 1) * 8192;
      unsigned short* Bsn = Bs + (cur ^ 1) * 8192;
#pragma unroll
      for (int it = 0; it < 4; ++it) {
        gll16(A  + (size_t)(m0 + rowX[it]) * KDIM + k0 + cbX[it], Asn + ldso[it]);
        gll16(Bt + (size_t)(n0 + rowX[it]) * KDIM + k0 + cbX[it], Bsn + ldso[it]);
      }
    }
#pragma unroll
    for (int kh = 0; kh < 2; ++kh) {
      int chk = (((kh * 4 + lg) ^ x7) << 3);
      bf16x8 af[4], bfv[4];
#pragma unroll
      for (int mf = 0; mf < 4; ++mf)
        af[mf] = *(const bf16x8*)&Asc[(wr * 64 + mf * 16 + li) * 64 + chk];
#pragma unroll
      for (int nf = 0; nf < 4; ++nf)
        bfv[nf] = *(const bf16x8*)&Bsc[(wc * 64 + nf * 16 + li) * 64 + chk];
#pragma unroll
      for (int mf = 0; mf < 4; ++mf)
#pragma unroll
        for (int nf = 0; nf < 4; ++nf)
          acc[mf][nf] = __builtin_amdgcn_mfma_f32_16x16x32_bf16(af[mf], bfv[nf], acc[mf][nf], 0, 0, 0);
    }
    if (pre) {
      asm volatile("s_waitcnt vmcnt(0)" ::: "memory");   // next buf landed
    }
    __builtin_amdgcn_sched_barrier(0);
    __builtin_amdgcn_s_barrier();                        // single barrier/K-step
  }
}

// -------- GEMM1: X @ Wcat^T with fused RoPE/sigmoid scatter epilogue --------
// L2-aware XCD n-stripe mapping: xcd = lin&7 owns 9 contiguous n-tiles
// (B-stripe 4.5 MB ~ L2-resident), sweeps all 32 m-tiles with n inner.
// V is written TRANSPOSED to global: vt[b][hk][d][s]  (enables plain-load PV)
__global__ __launch_bounds__(256) void ga_gemm_qkvg(const unsigned short* __restrict__ A,
                                                    const unsigned short* __restrict__ Bt,
                                                    unsigned short* __restrict__ qo,
                                                    unsigned short* __restrict__ ko,
                                                    unsigned short* __restrict__ vo,
                                                    unsigned short* __restrict__ go) {
  __shared__ unsigned short As[2 * 128 * 64];
  __shared__ unsigned short Bs[2 * 128 * 64];
  int tid = threadIdx.x, lane = tid & 63, wid = tid >> 6;
  int wr = wid >> 1, wc = wid & 1;
  int lin = blockIdx.x;
  int xcd = lin & 7, j = lin >> 3;            // j in 0..287
  int n0 = (xcd * 9 + (j % 9)) * 128;         // n-tile 0..71 (stripe of 9/XCD)
  int m0 = (j / 9) * 128;                     // m-tile 0..31
  f32x4 acc[4][4];
  f32x4 z = {0.f, 0.f, 0.f, 0.f};
#pragma unroll
  for (int i = 0; i < 4; ++i)
#pragma unroll
    for (int jj = 0; jj < 4; ++jj) acc[i][jj] = z;

  gemm_loop64<EE>(A, Bt, As, Bs, m0, n0, acc);

  int li = lane & 15, lg = lane >> 4;
  int nb = n0 + wc * 64;      // 64-aligned col block (single region, single head)
  int mb = m0 + wr * 64;
  bool isq = nb < 4096;
  bool isk = (nb >= 4096) && (nb < 4608);
  bool isv = (nb >= 4608) && (nb < 5120);
  // ln(10000)/32
  float invf0 = expf((float)li * -0.2878231366242601f);
  float invf1 = expf((float)(16 + li) * -0.2878231366242601f);

#pragma unroll
  for (int mf = 0; mf < 4; ++mf) {
#pragma unroll
    for (int r = 0; r < 4; ++r) {
      int m = mb + mf * 16 + lg * 4 + r;
      int bb = m >> 11, s = m & 2047;
      if (isv) {
        // transposed V write: vt[(bb*HKV+hk)*DD + d][s]
        int hk = (nb - 4608) >> 8, hdb = (nb - 4608) & 255;
        unsigned short* dst = vo + ((size_t)(bb * HKV_ + hk) * DD + hdb) * SS + s;
#pragma unroll
        for (int nf = 0; nf < 4; ++nf)
          dst[(size_t)(nf * 16 + li) * SS] = f2bf(acc[mf][nf][r]);
      } else if (!isq && !isk) {  // gate: sigmoid
        int h = (nb - 5120) >> 8, hdb = (nb - 5120) & 255;
        unsigned short* dst = go + ((size_t)(bb * H_ + h) * SS + s) * DD + hdb;
#pragma unroll
        for (int nf = 0; nf < 4; ++nf) {
          float x = acc[mf][nf][r];
          dst[nf * 16 + li] = f2bf(1.f / (1.f + __expf(-x)));
        }
      } else {
        int hdb; unsigned short* dst;
        if (isq) { int h = nb >> 8; hdb = nb & 255;
                   dst = qo + ((size_t)(bb * H_ + h) * SS + s) * DD; }
        else     { int hk = (nb - 4096) >> 8; hdb = (nb - 4096) & 255;
                   dst = ko + ((size_t)(bb * HKV_ + hk) * SS + s) * DD; }
        if (hdb == 0) {
          // RoPE: hd = nf*16+li in [0,64); partner hd^32 is acc[mf][nf^2]
#pragma unroll
          for (int nf = 0; nf < 2; ++nf) {
            int fi = nf * 16 + li;
            float ang = (float)s * (nf ? invf1 : invf0);
            float sn, cs;
            sincosf(ang, &sn, &cs);
            float x1 = acc[mf][nf][r], x2 = acc[mf][nf + 2][r];
            dst[fi]      = f2bf(x1 * cs - x2 * sn);
            dst[fi + 32] = f2bf(x2 * cs + x1 * sn);
          }
        } else {
#pragma unroll
          for (int nf = 0; nf < 4; ++nf) dst[hdb + nf * 16 + li] = f2bf(acc[mf][nf][r]);
        }
      }
    }
  }
}

// -------- GEMM2: attn @ Wo^T -> fp32 out --------
// L2-aware XCD m-stripe mapping: xcd owns 4 contiguous m-tiles (A-stripe
// 4 MB ~ L2-resident), sweeps all 16 n-tiles with m inner.
__global__ __launch_bounds__(256) void ga_gemm_out(const unsigned short* __restrict__ A,
                                                   const unsigned short* __restrict__ Bt,
                                                   float* __restrict__ C) {
  __shared__ unsigned short As[2 * 128 * 64];
  __shared__ unsigned short Bs[2 * 128 * 64];
  int tid = threadIdx.x, lane = tid & 63, wid = tid >> 6;
  int wr = wid >> 1, wc = wid & 1;
  int lin = blockIdx.x;
  int xcd = lin & 7, j = lin >> 3;            // j in 0..63
  int m0 = (xcd * 4 + (j & 3)) * 128;         // m-tile 0..31 (stripe of 4/XCD)
  int n0 = (j >> 2) * 128;                    // n-tile 0..15
  f32x4 acc[4][4];
  f32x4 z = {0.f, 0.f, 0.f, 0.f};
#pragma unroll
  for (int i = 0; i < 4; ++i)
#pragma unroll
    for (int jj = 0; jj < 4; ++jj) acc[i][jj] = z;

  gemm_loop64<HD>(A, Bt, As, Bs, m0, n0, acc);

  int li = lane & 15, lg = lane >> 4;
#pragma unroll
  for (int mf = 0; mf < 4; ++mf)
#pragma unroll
    for (int r = 0; r < 4; ++r) {
      int m = m0 + wr * 64 + mf * 16 + lg * 4 + r;
#pragma unroll
      for (int nf = 0; nf < 4; ++nf) {
        int n = n0 + wc * 64 + nf * 16 + li;
        C[(size_t)m * EE + n] = acc[mf][nf][r];
      }
    }
}

// ---- flash attention: swapped-QK 32x32 in-register softmax (m214 port) ----
// (unchanged from R13 — verified: XCD-local LPT dispatch, out of top-5)
__global__ __launch_bounds__(256) void ga_attn(const unsigned short* __restrict__ qb_,
                                               const unsigned short* __restrict__ kb,
                                               const unsigned short* __restrict__ vt,
                                               const unsigned short* __restrict__ gb,
                                               unsigned short* __restrict__ ob) {
  __shared__ unsigned short Ks[2][8192];   // [buf] 32 kv x 256 d (chunk-XOR row&7)
  __shared__ unsigned short Vs[2][8192];   // [buf] 256 d x 4 chunks (XOR d&3)
  __shared__ float Xch[4][32];             // per-wave scale broadcast
  int tid = threadIdx.x, lane = tid & 63, wid = tid >> 6;
  int col = lane & 31, hi = lane >> 5;
  int L = blockIdx.x;
  int xcd = L & 7, w = L >> 3;             // w in 0..63 within XCD
  int qblk = 15 - (w >> 2);                // LPT: heavy first, each qblk x4
  int bh = xcd * 4 + (w & 3);              // XCD-local heads (one (b,hk)/XCD)
  int q0 = qblk * 128;
  int b = bh >> 4, h = bh & 15, hk = h >> 3;
  const unsigned short* qp  = qb_ + ((size_t)(b * H_ + h) * SS) * DD;
  const unsigned short* kp  = kb + ((size_t)(b * HKV_ + hk) * SS) * DD;
  const unsigned short* vtp = vt + ((size_t)(b * HKV_ + hk) * DD) * SS;
  const unsigned short* gp  = gb + ((size_t)(b * H_ + h) * SS) * DD;

  // staging decode: 4 K-chunks + 4 V-chunks of 16B per thread per tile
  int kgo[4], vgo[4], lob[4];
#pragma unroll
  for (int it = 0; it < 4; ++it) {
    int c = it * 256 + tid;                          // chunk slot 0..1023
    int kr = c >> 5, c16 = c & 31;                   // K: 32 rows x 32 chunks
    kgo[it] = kr * DD + ((c16 ^ (kr & 7)) << 3);     // pre-swizzled source
    int vd = c >> 2;                                 // V: 256 rows x 4 chunks
    int cmg = (c & 3) ^ (vd & 3);
    vgo[it] = vd * SS + (cmg << 3);                  // 64B-coalesced source
    lob[it] = (it * 256 + wid * 64) * 8;             // wave-uniform LDS base
  }

  // Q fragments (B-operand): lane holds Q[q = qwave+col][d = ks*16 + hi*8 ..]
  int qwave = q0 + wid * 32;
  bf16x8 qf[16];
#pragma unroll
  for (int ks = 0; ks < 16; ++ks)
    qf[ks] = *(const bf16x8*)(qp + (size_t)(qwave + col) * DD + ks * 16 + hi * 8);

  f32x16 acc[8];
#pragma unroll
  for (int d8 = 0; d8 < 8; ++d8)
#pragma unroll
    for (int r = 0; r < 16; ++r) acc[d8][r] = 0.f;
  float mrun = -1e30f, lrun = 0.f;

  int nt = q0 / 32 + 4;
  int vs0 = ((hi) ^ (col & 3)) << 3;       // kstep0 chunk offset (elems)
  int vs1 = ((2 + hi) ^ (col & 3)) << 3;   // kstep1

  // prologue: stage tile 0 into buffer 0, wait, single barrier
#pragma unroll
  for (int it = 0; it < 4; ++it) {
    gll16(kp + kgo[it], &Ks[0][lob[it]]);
    gll16(vtp + vgo[it], &Vs[0][lob[it]]);
  }
  asm volatile("s_waitcnt vmcnt(0)" ::: "memory");
  __builtin_amdgcn_s_barrier();

  for (int t = 0; t < nt; ++t) {
    int kv0 = t * 32;
    int cur = t & 1;
    bool pre = (t + 1 < nt);
    if (pre) {
      int kvn = kv0 + 32;
#pragma unroll
      for (int it = 0; it < 4; ++it) {
        gll16(kp + (size_t)kvn * DD + kgo[it], &Ks[cur ^ 1][lob[it]]);
        gll16(vtp + kvn + vgo[it],             &Vs[cur ^ 1][lob[it]]);
      }
    }
    if (kv0 <= qwave + 31) {                  // wave-uniform causal activity
      // ---- swapped QK^T: S[kv][q] = mfma(A=K, B=Q) ----
      f32x16 sc;
#pragma unroll
      for (int r = 0; r < 16; ++r) sc[r] = 0.f;
      const unsigned short* kbase = &Ks[cur][col * 256];
      __builtin_amdgcn_s_setprio(1);
#pragma unroll
      for (int ks = 0; ks < 16; ++ks) {
        bf16x8 kfr = *(const bf16x8*)(kbase + (((ks * 2 + hi) ^ (col & 7)) << 3));
        sc = __builtin_amdgcn_mfma_f32_32x32x16_bf16(kfr, qf[ks], sc, 0, 0, 0);
      }
      __builtin_amdgcn_s_setprio(0);
      // ---- scale + causal mask (kv = crow(r,hi), q = col) ----
      bool needmask = (kv0 + 31 > qwave);
#pragma unroll
      for (int r = 0; r < 16; ++r) {
        int kvg = kv0 + (r & 3) + 8 * (r >> 2) + 4 * hi;
        float v = sc[r] * 0.0625f;
        if (needmask && kvg > qwave + col) v = -1e30f;
        sc[r] = v;
      }
      // ---- row max: in-lane tree + one partner exchange ----
      float pm = fmaxf(sc[0], sc[1]);
#pragma unroll
      for (int r = 2; r < 16; ++r) pm = fmaxf(pm, sc[r]);
      pm = fmaxf(pm, __shfl_xor(pm, 32));
      // ---- defer-max (THR=8); rare O-rescale via per-wave LDS broadcast ----
      if (!__all(pm - mrun <= 8.f)) {
        float nm = fmaxf(mrun, pm);
        float scl = __expf(mrun - nm);
        mrun = nm;
        lrun *= scl;
        if (lane < 32) Xch[wid][lane] = scl;
#pragma unroll
        for (int r = 0; r < 16; ++r) {
          float s2 = Xch[wid][(r & 3) + 8 * (r >> 2) + 4 * hi];
#pragma unroll
          for (int d8 = 0; d8 < 8; ++d8) acc[d8][r] *= s2;
        }
      }
      // ---- exp + sum (in-lane + one exchange) ----
      float rs = 0.f;
#pragma unroll
      for (int r = 0; r < 16; ++r) { float e = __expf(sc[r] - mrun); sc[r] = e; rs += e; }
      rs += __shfl_xor(rs, 32);
      lrun += rs;
      // ---- pack P to bf16 A-frags; one-hop exchanges across lane^32 ----
      unsigned w2[8];
#pragma unroll
      for (int jj = 0; jj < 8; ++jj)
        w2[jj] = ((unsigned)f2bf(sc[2 * jj + 1]) << 16) | (unsigned)f2bf(sc[2 * jj]);
      unsigned x0 = (unsigned)__shfl_xor((int)w2[2], 32);
      unsigned x1 = (unsigned)__shfl_xor((int)w2[3], 32);
      unsigned x2 = (unsigned)__shfl_xor((int)w2[0], 32);
      unsigned x3 = (unsigned)__shfl_xor((int)w2[1], 32);
      unsigned x4 = (unsigned)__shfl_xor((int)w2[6], 32);
      unsigned x5 = (unsigned)__shfl_xor((int)w2[7], 32);
      unsigned x6 = (unsigned)__shfl_xor((int)w2[4], 32);
      unsigned x7 = (unsigned)__shfl_xor((int)w2[5], 32);
      union { unsigned u[4]; bf16x8 v; } pa0, pa1;
      pa0.u[0] = hi ? x0 : w2[0];
      pa0.u[1] = hi ? x1 : w2[1];
      pa0.u[2] = hi ? w2[2] : x2;
      pa0.u[3] = hi ? w2[3] : x3;
      pa1.u[0] = hi ? x4 : w2[4];
      pa1.u[1] = hi ? x5 : w2[5];
      pa1.u[2] = hi ? w2[6] : x6;
      pa1.u[3] = hi ? w2[7] : x7;
      // ---- PV: O[q][d] += P @ V ----
      const unsigned short* vb = &Vs[cur][0];
      __builtin_amdgcn_s_setprio(1);
#pragma unroll
      for (int d8 = 0; d8 < 8; ++d8) {
        int rb = (d8 * 32 + col) * 32;
        bf16x8 bv0 = *(const bf16x8*)(vb + rb + vs0);
        bf16x8 bv1 = *(const bf16x8*)(vb + rb + vs1);
        acc[d8] = __builtin_amdgcn_mfma_f32_32x32x16_bf16(pa0.v, bv0, acc[d8], 0, 0, 0);
        acc[d8] = __builtin_amdgcn_mfma_f32_32x32x16_bf16(pa1.v, bv1, acc[d8], 0, 0, 0);
      }
      __builtin_amdgcn_s_setprio(0);
    }
    if (pre) {
      asm volatile("s_waitcnt vmcnt(0)" ::: "memory");   // next tile landed
    }
    __builtin_amdgcn_sched_barrier(0);
    __builtin_amdgcn_s_barrier();            // single barrier per tile
  }
  // ---- epilogue: normalize (broadcast 1/l), gate, store ----
  if (lane < 32) Xch[wid][lane] = 1.f / lrun;
#pragma unroll
  for (int r = 0; r < 16; ++r) {
    int crow = (r & 3) + 8 * (r >> 2) + 4 * hi;
    float inv2 = Xch[wid][crow];
    int qrow = qwave + crow;
    const unsigned short* gr = gp + (size_t)qrow * DD;
    unsigned short* orow = ob + ((size_t)(b * SS + qrow)) * HD + h * DD;
#pragma unroll
    for (int d8 = 0; d8 < 8; ++d8) {
      int d = d8 * 32 + col;
      float gv = bf2f(gr[d]);
      orow[d] = f2bf(acc[d8][r] * inv2 * gv);
    }
  }
}

extern "C" void kernel_launch(void* const* d_in, const int* in_sizes, int n_in,
                              void* d_out, int out_size, void* d_ws, size_t ws_size,
                              hipStream_t stream) {
  (void)in_sizes; (void)n_in; (void)out_size;
  const float* hs = (const float*)d_in[0];
  const float* Wq = (const float*)d_in[1];
  const float* Wk = (const float*)d_in[2];
  const float* Wv = (const float*)d_in[3];
  const float* Wg = (const float*)d_in[4];
  const float* Wo = (const float*)d_in[5];
  float* out = (float*)d_out;

  // workspace layout (bytes)
  const size_t off_X    = 0;                       // 4096x2048 bf16
  const size_t off_Wcat = off_X    + 16777216;     // 9216x2048 bf16 (transposed)
  const size_t off_Wot  = off_Wcat + 37748736;     // 2048x4096 bf16 (transposed)
  const size_t off_q    = off_Wot  + 16777216;     // B,H,S,D bf16
  const size_t off_k    = off_q    + 33554432;     // B,HKV,S,D
  const size_t off_v    = off_k    + 4194304;      // B,HKV,D,S (TRANSPOSED)
  const size_t off_g    = off_v    + 4194304;      // B,H,S,D
  const size_t off_attn = off_g    + 33554432;     // 4096x4096 bf16
  const size_t need     = off_attn + 33554432;     // ~172 MB
  if (ws_size < need) return;  // insufficient scratch: leave output poisoned

  char* ws = (char*)d_ws;
  unsigned short* Xbf   = (unsigned short*)(ws + off_X);
  unsigned short* Wcat  = (unsigned short*)(ws + off_Wcat);
  unsigned short* Wot   = (unsigned short*)(ws + off_Wot);
  unsigned short* qbf   = (unsigned short*)(ws + off_q);
  unsigned short* kbf   = (unsigned short*)(ws + off_k);
  unsigned short* vbf   = (unsigned short*)(ws + off_v);
  unsigned short* gbf   = (unsigned short*)(ws + off_g);
  unsigned short* attnb = (unsigned short*)(ws + off_attn);

  // 1) convert hidden_states to bf16
  ga_cvt<<<8192, 256, 0, stream>>>(hs, Xbf, MTOK * EE);
  // 2) pack weights (transposed, bf16)
  ga_pack_qkvg<<<dim3(144, 32), 256, 0, stream>>>(Wq, Wk, Wv, Wg, Wcat);
  ga_transpose_wo<<<dim3(32, 64), 256, 0, stream>>>(Wo, Wot, HD, EE);
  // 3) fused QKVG projection + RoPE + sigmoid (BK=64 depth-1 dbuf)
  ga_gemm_qkvg<<<dim3(2304), 256, 0, stream>>>(Xbf, Wcat, qbf, kbf, vbf, gbf);
  // 4) causal GQA flash attention + gating (XCD-local LPT dispatch)
  ga_attn<<<dim3(512), 256, 0, stream>>>(qbf, kbf, vbf, gbf, attnb);
  // 5) output projection (BK=64 depth-1 dbuf, fp32 out)
  ga_gemm_out<<<dim3(512), 256, 0, stream>>>(attnb, Wot, out);
}